// Round 3
// baseline (256.041 us; speedup 1.0000x reference)
//
#include <hip/hip_runtime.h>
#include <hip/hip_bf16.h>

#define N_ 50000
#define E_ 800000
#define IN_ 128
#define OUT_ 128
#define ASSIGN_ 256
#define B_ 32
#define KTOT 256     // 2*IN
#define JTOT 384     // OUT + ASSIGN
#define HCHUNK 32
#define ACHUNK 32
#define AST 72       // k_adjm LDS row stride in u16
#define NXP ((N_ + 127) / 128)       // 391 row panels
#define NGB (NXP * 3)                // 1173 gemm blocks
#define NCVX 6250                    // (N*128/4)/256 exact
#define NAGG (1563 * 8)              // agg blocks: 8-node groups, xcd-striped

// edge bucket sort
#define NBKT 128
#define NPB 391
#define BCAP 7000
#define EPB 4096
#define NBLK_A ((E_ + EPB - 1) / EPB)  // 196

typedef __attribute__((ext_vector_type(8))) short short8;
typedef __attribute__((ext_vector_type(4))) float f32x4;
typedef __attribute__((ext_vector_type(2))) float f32x2;
typedef __attribute__((ext_vector_type(4))) unsigned short ushort4v;
typedef __attribute__((ext_vector_type(2))) unsigned short ushort2v;
typedef unsigned short u16;

__device__ inline unsigned short f2bf(float v) {
    union { float f; unsigned u; } a;
    a.f = v;
    unsigned r = a.u + 0x7fff + ((a.u >> 16) & 1);  // RNE
    return (unsigned short)(r >> 16);
}
__device__ inline float bf2f(unsigned short b) {
    union { unsigned u; float f; } a;
    a.u = ((unsigned)b) << 16;
    return a.f;
}

// ---- fp8 e4m3 encode (RNE via f32 bit trick; |v| < 448 assumed) ----
__device__ inline unsigned enc8(float v) {
    union { float f; unsigned u; } a;
    a.f = v * 0x1p-120f;
    unsigned b = a.u;
    unsigned r = b + 0x7FFFF + ((b >> 20) & 1);
    return ((r >> 20) & 0x7F) | ((b >> 24) & 0x80);
}
// ---- fp8 e4m3 pair decode ----
__device__ inline float2 dec8x2(unsigned short p) {
#if defined(__has_builtin) && __has_builtin(__builtin_amdgcn_cvt_pk_f32_fp8)
    f32x2 r = __builtin_amdgcn_cvt_pk_f32_fp8((int)(unsigned)p, false);
    return make_float2(r.x, r.y);
#else
    unsigned u0 = p & 0xffu, u1 = (p >> 8) & 0xffu;
    union { unsigned u; float f; } a, b;
    a.u = ((u0 & 0x80u) << 24) | ((u0 & 0x7fu) << 20);
    b.u = ((u1 & 0x80u) << 24) | ((u1 & 0x7fu) << 20);
    return make_float2(a.f * 0x1p+120f, b.f * 0x1p+120f);
#endif
}

// ---------------- x -> bf16 + fp8 (half-split layout) + bktFill init + W prep (fused) ----
// xq layout: xq[half][node][64] fp8 — each 3.2 MB half is per-XCD-L2-resident for k_agg.
__global__ __launch_bounds__(256) void k_convx(const float* __restrict__ x,
                                               unsigned short* __restrict__ xhi,
                                               unsigned char* __restrict__ xq,
                                               int* __restrict__ bktFill,
                                               const float* __restrict__ We,
                                               const float* __restrict__ be,
                                               const float* __restrict__ Wp,
                                               const float* __restrict__ bp,
                                               unsigned short* __restrict__ WThi,
                                               float* __restrict__ bias) {
    int bid = blockIdx.x;
    int t = threadIdx.x;
    if (bid >= NCVX) {  // k_prep tail blocks
        int idx = (bid - NCVX) * 256 + t;
        if (idx < JTOT * KTOT) {
            int j = idx / KTOT, k = idx - j * KTOT;
            float v = (j < 128) ? We[k * 128 + j] : Wp[k * 256 + (j - 128)];
            WThi[idx] = f2bf(v);
        }
        if (idx < JTOT) bias[idx] = (idx < 128) ? be[idx] : bp[idx - 128];
        return;
    }
    if (bid == 0 && t < NBKT) bktFill[t] = t * BCAP;
    int i4 = (bid * 256 + t) * 4;
    if (i4 >= N_ * 128) return;
    float4 v = *(const float4*)(x + i4);
    ushort4v h;
    h.x = f2bf(v.x); h.y = f2bf(v.y); h.z = f2bf(v.z); h.w = f2bf(v.w);
    *(ushort4v*)(xhi + i4) = h;
    unsigned q = enc8(v.x) | (enc8(v.y) << 8) | (enc8(v.z) << 16) | (enc8(v.w) << 24);
    int f = i4 & 127, node = i4 >> 7;
    int half = f >> 6, fo = f & 63;
    *(unsigned*)(xq + ((size_t)half * N_ + node) * 64 + fo) = q;
}

// ---------------- phase A: bin edges by dst-range ----------------
__global__ __launch_bounds__(256) void k_binA(const int* __restrict__ ei,
                                              int* __restrict__ bktFill,
                                              int2* __restrict__ ebkt) {
    __shared__ int lh[NBKT], lbase[NBKT], lofs[NBKT];
    int t = threadIdx.x;
    int e0 = blockIdx.x * EPB;
    if (t < NBKT) { lh[t] = 0; lofs[t] = 0; }
    __syncthreads();
    int ss[16], dd[16];
#pragma unroll
    for (int i = 0; i < 16; i++) {
        int e = e0 + i * 256 + t;
        ss[i] = 0; dd[i] = -1;
        if (e < E_) {
            ss[i] = ei[e];
            dd[i] = ei[E_ + e];
            atomicAdd(&lh[dd[i] / NPB], 1);
        }
    }
    __syncthreads();
    if (t < NBKT) lbase[t] = atomicAdd(&bktFill[t], lh[t]);
    __syncthreads();
#pragma unroll
    for (int i = 0; i < 16; i++) {
        if (dd[i] >= 0) {
            int b = dd[i] / NPB;
            int o = atomicAdd(&lofs[b], 1);
            ebkt[lbase[b] + o] = make_int2(ss[i], dd[i]);
        }
    }
}

// ---------------- phase B0: per-bucket deg histogram + local exclusive scan ----------------
__global__ __launch_bounds__(256) void k_binB0(const int* __restrict__ bktFill,
                                               const int2* __restrict__ ebkt,
                                               int* __restrict__ locOff,
                                               int* __restrict__ bucketTotal) {
    __shared__ int ldeg[NPB];
    __shared__ int lscan[512];
    int b = blockIdx.x, t = threadIdx.x;
    for (int i = t; i < NPB; i += 256) ldeg[i] = 0;
    __syncthreads();
    int base = b * BCAP;
    int cnt = bktFill[b] - base;
    int n0 = b * NPB;
    for (int j = t; j < cnt; j += 256)
        atomicAdd(&ldeg[ebkt[base + j].y - n0], 1);
    __syncthreads();
    lscan[t] = (t < NPB) ? ldeg[t] : 0;
    lscan[t + 256] = (t + 256 < NPB) ? ldeg[t + 256] : 0;
    __syncthreads();
    for (int off = 1; off < 512; off <<= 1) {
        int x0 = lscan[t];
        int x1 = lscan[t + 256];
        int a0 = (t >= off) ? lscan[t - off] : 0;
        int a1 = (t + 256 >= off) ? lscan[t + 256 - off] : 0;
        __syncthreads();
        lscan[t] = x0 + a0;
        lscan[t + 256] = x1 + a1;
        __syncthreads();
    }
    for (int i = t; i < NPB; i += 256) {
        int n = n0 + i;
        if (n < N_) locOff[n] = (i == 0) ? 0 : lscan[i - 1];
    }
    if (t == 0) bucketTotal[b] = lscan[NPB - 1];
}

// ---------------- tiny scan over 128 bucket totals ----------------
__global__ __launch_bounds__(128) void k_scanS(const int* __restrict__ bucketTotal,
                                               int* __restrict__ bucketBase,
                                               int* __restrict__ rowStart) {
    __shared__ int sh[128];
    int t = threadIdx.x;
    sh[t] = bucketTotal[t];
    __syncthreads();
    for (int off = 1; off < 128; off <<= 1) {
        int x = sh[t];
        int a = (t >= off) ? sh[t - off] : 0;
        __syncthreads();
        sh[t] = x + a;
        __syncthreads();
    }
    bucketBase[t] = (t == 0) ? 0 : sh[t - 1];
    if (t == 0) rowStart[N_] = E_;
}

// ---------------- phase B1: write absolute rowStart + CSR scatter (src AND dst) ----------------
__global__ __launch_bounds__(256) void k_binB1(const int* __restrict__ bktFill,
                                               const int2* __restrict__ ebkt,
                                               const int* __restrict__ locOff,
                                               const int* __restrict__ bucketBase,
                                               int* __restrict__ rowStart,
                                               int* __restrict__ csr_src,
                                               int* __restrict__ csr_dst) {
    __shared__ int lfill[NPB];
    int b = blockIdx.x, t = threadIdx.x;
    int base0 = bucketBase[b];
    int n0 = b * NPB;
    for (int i = t; i < NPB; i += 256) {
        int n = n0 + i;
        if (n < N_) {
            int lo = locOff[n];
            lfill[i] = lo;
            rowStart[n] = base0 + lo;
        }
    }
    __syncthreads();
    int base = b * BCAP;
    int cnt = bktFill[b] - base;
    for (int j = t; j < cnt; j += 256) {
        int2 sd = ebkt[base + j];
        int p = base0 + atomicAdd(&lfill[sd.y - n0], 1);
        csr_src[p] = sd.x;
        csr_dst[p] = sd.y;
    }
}

// ---------------- neigh mean: pipelined gather (coalesced index prefetch + shfl bcast) ------
// blockIdx % 8 == XCD. XCDs 0-3 gather half-0 (3.2 MB), XCDs 4-7 half-1: L2-resident.
// Lane l of each 32-lane group loads csr_src[w0+l] (coalesced, 32 edges ahead);
// per-edge index comes from __shfl — no index-load on the gather critical path.
__global__ __launch_bounds__(256) void k_agg(const unsigned char* __restrict__ xq,
                                             const int* __restrict__ rowStart,
                                             const int* __restrict__ csr_src,
                                             unsigned short* __restrict__ nhi) {
    int b = blockIdx.x;
    int xcd = b & 7;
    int half = xcd >> 2;
    int gi = (b >> 3) * 4 + (xcd & 3);       // node-group 0..6249 within half
    int t = threadIdx.x;
    int node = gi * 8 + (t >> 5);
    int l = t & 31;
    int gb = t & 32;                          // group's base lane within the wave
    if (node >= N_) return;
    const unsigned char* base = xq + (size_t)half * N_ * 64;
    int a = rowStart[node], bnd = rowStart[node + 1];
    float ax = 0.f, ay = 0.f;
    for (int w0 = a; w0 < bnd; w0 += 32) {
        int j = w0 + l;
        int myidx = (j < bnd) ? csr_src[j] : -1;   // coalesced 128B per group
        int m = bnd - w0; if (m > 32) m = 32;
        for (int e = 0; e < m; e += 8) {
            unsigned short p[8] = {0, 0, 0, 0, 0, 0, 0, 0};
#pragma unroll
            for (int i = 0; i < 8; i++) {
                int s = __shfl(myidx, gb + e + i, 64);
                if (s >= 0)
                    p[i] = *(const unsigned short*)(base + (size_t)s * 64 + l * 2);
            }
#pragma unroll
            for (int i = 0; i < 8; i++) {           // dec8x2(0) == 0: self-guarding
                float2 f = dec8x2(p[i]);
                ax += f.x;
                ay += f.y;
            }
        }
    }
    float inv = 1.0f / (float)max(bnd - a, 1);
    ushort2v h;
    h.x = f2bf(ax * inv);
    h.y = f2bf(ay * inv);
    *(ushort2v*)(nhi + (size_t)node * 128 + half * 64 + l * 2) = h;
}

// ---------------- uniform 1-pass bf16 MFMA GEMM, XCD-swizzled, LDS epilogue ------
#define LDA 40  // 80 B rows
__global__ __launch_bounds__(256) void k_gemm(const unsigned short* __restrict__ xhi,
                                              const unsigned short* __restrict__ nhi,
                                              const unsigned short* __restrict__ WThi,
                                              const float* __restrict__ bias,
                                              unsigned short* __restrict__ embed,
                                              unsigned short* __restrict__ plog) {
    __shared__ __align__(16) union {
        struct { u16 Ah[128][LDA]; u16 Bh[128][LDA]; } s;
        u16 ep[64 * 128];  // 16 KB epilogue tile (64 rows x 128 cols)
    } sm;
    int t = threadIdx.x;
    int wave = t >> 6, lane = t & 63;
    int wm = wave >> 1, wn = wave & 1;
    int q = lane >> 4, lr = lane & 15;

    int id = blockIdx.x;
    int xi, cc;
    if (id < (NXP / 8) * 24) {           // 1152
        xi = (id / 24) * 8 + (id & 7);
        cc = (id % 24) >> 3;
    } else {
        int r2 = id - (NXP / 8) * 24;    // 0..20 over 7 tail panels
        xi = (NXP / 8) * 8 + r2 % (NXP % 8);
        cc = r2 / (NXP % 8);
    }
    int row0 = xi * 128;
    int col0 = cc * 128;

    f32x4 acc[4][4] = {};
    int smr = t >> 1;
    int kc = (t & 1) * 16;

    for (int kt = 0; kt < KTOT; kt += 32) {
        const u16* Ah_src = (kt < 128) ? xhi : nhi;
        int kb = (kt & 127) + kc;
        int node = row0 + smr;
        short8 vh0 = {}, vh1 = {};
        if (node < N_) {
            const short8* ph = (const short8*)(Ah_src + (size_t)node * 128 + kb);
            vh0 = ph[0]; vh1 = ph[1];
        }
        *(short8*)&sm.s.Ah[smr][kc] = vh0;
        *(short8*)&sm.s.Ah[smr][kc + 8] = vh1;
        {
            const short8* ph = (const short8*)(WThi + (size_t)(col0 + smr) * 256 + kt + kc);
            short8 wh0 = ph[0], wh1 = ph[1];
            *(short8*)&sm.s.Bh[smr][kc] = wh0;
            *(short8*)&sm.s.Bh[smr][kc + 8] = wh1;
        }
        __syncthreads();

        short8 afh[4];
#pragma unroll
        for (int mi = 0; mi < 4; mi++) {
            int r = wm * 64 + mi * 16 + lr;
            afh[mi] = *(const short8*)&sm.s.Ah[r][q * 8];
        }
#pragma unroll
        for (int ni = 0; ni < 4; ni++) {
            int r = wn * 64 + ni * 16 + lr;
            short8 bfh = *(const short8*)&sm.s.Bh[r][q * 8];
#pragma unroll
            for (int mi = 0; mi < 4; mi++)
                acc[mi][ni] = __builtin_amdgcn_mfma_f32_16x16x32_bf16(afh[mi], bfh, acc[mi][ni], 0, 0, 0);
        }
        __syncthreads();
    }

    // epilogue: two 64-row halves through LDS, full-line coalesced stores
    for (int half = 0; half < 2; half++) {
        __syncthreads();
        if (wm == half) {
#pragma unroll
            for (int mi = 0; mi < 4; mi++)
#pragma unroll
                for (int ni = 0; ni < 4; ni++) {
                    int lcol = wn * 64 + ni * 16 + lr;
                    float bj = bias[col0 + lcol];
#pragma unroll
                    for (int r = 0; r < 4; r++) {
                        int lrow = mi * 16 + q * 4 + r;
                        sm.ep[lrow * 128 + lcol] = f2bf(acc[mi][ni][r] + bj);
                    }
                }
        }
        __syncthreads();
#pragma unroll
        for (int i = 0; i < 4; i++) {
            int chunk = i * 256 + t;          // 0..1023
            int lrow = chunk >> 4;            // 64 rows x 16 chunks
            int lco = (chunk & 15) * 8;       // u16 offset
            int grow = row0 + half * 64 + lrow;
            if (grow < N_) {
                short8 v = *(const short8*)&sm.ep[lrow * 128 + lco];
                if (col0 < 128)
                    *(short8*)(embed + (size_t)grow * 128 + lco) = v;
                else
                    *(short8*)(plog + (size_t)grow * 256 + (col0 - 128) + lco) = v;
            }
        }
    }
}

// ---------------- double softmax -> compact r8[N][8] (fp32 + bf16 copy) ----------------
__global__ __launch_bounds__(256) void k_r(const unsigned short* __restrict__ plog,
                                           const int* __restrict__ batch,
                                           float* __restrict__ r8,
                                           unsigned short* __restrict__ r8b) {
    int node = blockIdx.x * 4 + (threadIdx.x >> 6);
    int lane = threadIdx.x & 63;
    if (node >= N_) return;
    ushort4v p4 = *(const ushort4v*)(plog + (size_t)node * 256 + lane * 4);
    float px = bf2f(p4.x), py = bf2f(p4.y), pz = bf2f(p4.z), pw = bf2f(p4.w);
    float m = fmaxf(fmaxf(px, py), fmaxf(pz, pw));
    for (int off = 32; off; off >>= 1) m = fmaxf(m, __shfl_xor(m, off, 64));
    float s = expf(px - m) + expf(py - m) + expf(pz - m) + expf(pw - m);
    for (int off = 32; off; off >>= 1) s += __shfl_xor(s, off, 64);
    int g = batch[node];
    float v = 0.f;
    if (lane < 8) v = expf(bf2f(plog[(size_t)node * 256 + g * 8 + lane]) - m) / s;
    float M2 = v;
    for (int off = 4; off; off >>= 1) M2 = fmaxf(M2, __shfl_xor(M2, off, 64));
    float e = expf(v - M2);
    float Sg = e;
    for (int off = 4; off; off >>= 1) Sg += __shfl_xor(Sg, off, 64);
    float D2 = Sg + 248.0f * expf(-M2);
    float r = e / (Sg + 1e-13f * D2);
    if (lane < 8) {
        r8[node * 8 + lane] = r;
        r8b[node * 8 + lane] = f2bf(r);
    }
}

// ---------------- h partials (bf16 embed) ----------------
__global__ __launch_bounds__(256) void k_h_part(const unsigned short* __restrict__ embed,
                                                const float* __restrict__ r8,
                                                float* __restrict__ partH) {
    int g = blockIdx.x;
    int c = blockIdx.y;
    int t = threadIdx.x;
    int o = t & 127, half = t >> 7;
    int n0g = (g * N_ + 31) >> 5;
    int n1g = ((g + 1) * N_ + 31) >> 5;
    int len = n1g - n0g;
    int a = n0g + (len * c) / HCHUNK;
    int b = n0g + (len * (c + 1)) / HCHUNK;
    float a0 = 0.f, a1 = 0.f, a2 = 0.f, a3 = 0.f;
#pragma unroll 4
    for (int n = a; n < b; n++) {
        float e = bf2f(embed[(size_t)n * 128 + o]);
        const float* rr = r8 + n * 8 + half;
        a0 += rr[0] * e;
        a1 += rr[2] * e;
        a2 += rr[4] * e;
        a3 += rr[6] * e;
    }
    float* pb = partH + (g * HCHUNK + c) * 1024;
    pb[(half + 0) * 128 + o] = a0;
    pb[(half + 2) * 128 + o] = a1;
    pb[(half + 4) * 128 + o] = a2;
    pb[(half + 6) * 128 + o] = a3;
}

// ---------------- adj via MFMA over edge tiles (zero-on-exit, csr_dst gather) ----------------
__global__ __launch_bounds__(256) void k_adjm(const int* __restrict__ rowStart,
                                              const int* __restrict__ csr_src,
                                              const int* __restrict__ csr_dst,
                                              const unsigned short* __restrict__ r8b,
                                              float* __restrict__ partAdj) {
    __shared__ __align__(16) unsigned short Ab[256 * AST];  // [col=gs*8+a][e]
    __shared__ __align__(16) unsigned short Bb[16 * AST];   // [n=b][e]
    int gd = blockIdx.x, c = blockIdx.y;
    int t = threadIdx.x;
    int wave = t >> 6, lane = t & 63;
    int q = lane >> 4, lr = lane & 15;
    int n0g = (gd * N_ + 31) >> 5;
    int n1g = ((gd + 1) * N_ + 31) >> 5;
    int len = n1g - n0g;
    int na = n0g + (len * c) / ACHUNK;
    int nb = n0g + (len * (c + 1)) / ACHUNK;
    int j0 = rowStart[na], j1 = rowStart[nb];

    // zero LDS ONCE; per-tile invariants maintained by zero-on-exit below
    uint4 z = {0, 0, 0, 0};
#pragma unroll
    for (int i = 0; i < 9; i++) *(uint4*)&Ab[(i * 256 + t) * 8] = z;
    if (t < 144) *(uint4*)&Bb[t * 8] = z;
    __syncthreads();

    f32x4 acc[4] = {};
    int el = t >> 2;
    int ap = t & 3;

    for (int jt = j0; jt < j1; jt += 64) {
        int j = jt + el;
        int ca = -1;
        if (j < j1) {
            int s = csr_src[j];
            int d = csr_dst[j];
            int gs = (s * B_) / N_;
            unsigned sv = *(const unsigned*)(r8b + (size_t)s * 8 + ap * 2);
            unsigned dv = *(const unsigned*)(r8b + (size_t)d * 8 + ap * 2);
            ca = gs * 8 + ap * 2;
            Ab[ca * AST + el] = (unsigned short)sv;
            Ab[(ca + 1) * AST + el] = (unsigned short)(sv >> 16);
            Bb[(ap * 2) * AST + el] = (unsigned short)dv;
            Bb[(ap * 2 + 1) * AST + el] = (unsigned short)(dv >> 16);
        }
        __syncthreads();
        short8 bf0 = *(const short8*)&Bb[lr * AST + q * 8];
        short8 bf1 = *(const short8*)&Bb[lr * AST + 32 + q * 8];
#pragma unroll
        for (int mi = 0; mi < 4; mi++) {
            int col = (wave * 4 + mi) * 16 + lr;
            short8 a0 = *(const short8*)&Ab[col * AST + q * 8];
            short8 a1 = *(const short8*)&Ab[col * AST + 32 + q * 8];
            acc[mi] = __builtin_amdgcn_mfma_f32_16x16x32_bf16(a0, bf0, acc[mi], 0, 0, 0);
            acc[mi] = __builtin_amdgcn_mfma_f32_16x16x32_bf16(a1, bf1, acc[mi], 0, 0, 0);
        }
        __syncthreads();
        if (ca >= 0) {  // zero-on-exit: clear exactly the slots this thread wrote
            Ab[ca * AST + el] = 0;
            Ab[(ca + 1) * AST + el] = 0;
            Bb[(ap * 2) * AST + el] = 0;
            Bb[(ap * 2 + 1) * AST + el] = 0;
        }
        __syncthreads();
    }

    float* pb = partAdj + (gd * ACHUNK + c) * 2048;
    if (lr < 8) {
#pragma unroll
        for (int mi = 0; mi < 4; mi++) {
            int mbase = (wave * 4 + mi) * 16 + q * 4;
#pragma unroll
            for (int r = 0; r < 4; r++)
                pb[(mbase + r) * 8 + lr] = acc[mi][r];
        }
    }
}

// ---------------- fused adj + h reduce ----------------
__global__ __launch_bounds__(256) void k_red(const float* __restrict__ partAdj,
                                             const float* __restrict__ partH,
                                             float* __restrict__ out) {
    int o = blockIdx.x * 256 + threadIdx.x;
    if (o < 256 * 256) {
        int row = o >> 8, col = o & 255;
        int gd = col >> 3, b = col & 7;
        int li = row * 8 + b;
        float s = 0.f;
#pragma unroll
        for (int c = 0; c < ACHUNK; c++) s += partAdj[(gd * ACHUNK + c) * 2048 + li];
        out[o] = s;
    } else {
        int idx = o - 256 * 256;            // < 32768 by grid sizing
        int g = idx >> 10;
        int local = idx & 1023;
        float s = 0.f;
#pragma unroll
        for (int c = 0; c < HCHUNK; c++) s += partH[(g * HCHUNK + c) * 1024 + local];
        out[256 * 256 + idx] = s;
    }
}

extern "C" void kernel_launch(void* const* d_in, const int* in_sizes, int n_in,
                              void* d_out, int out_size, void* d_ws, size_t ws_size,
                              hipStream_t stream) {
    const float* x = (const float*)d_in[0];
    const int* ei = (const int*)d_in[1];
    const int* batch = (const int*)d_in[2];
    const float* We = (const float*)d_in[3];
    const float* be = (const float*)d_in[4];
    const float* Wp = (const float*)d_in[5];
    const float* bp = (const float*)d_in[6];
    float* out = (float*)d_out;  // [adj 256*256 | h 256*128]

    char* w = (char*)d_ws;
    auto alloc = [&](size_t bytes) -> char* {
        char* p = w;
        w += (bytes + 255) & ~(size_t)255;
        return p;
    };
    unsigned short* xhi = (unsigned short*)alloc((size_t)N_ * 128 * 2);
    unsigned char* xq = (unsigned char*)alloc((size_t)N_ * 128);
    unsigned short* nhi = (unsigned short*)alloc((size_t)N_ * 128 * 2);
    unsigned short* WThi = (unsigned short*)alloc((size_t)JTOT * KTOT * 2);
    unsigned short* embed = (unsigned short*)alloc((size_t)N_ * 128 * 2);
    unsigned short* plog = (unsigned short*)alloc((size_t)N_ * 256 * 2);
    float* r8 = (float*)alloc((size_t)N_ * 8 * 4);
    unsigned short* r8b = (unsigned short*)alloc((size_t)N_ * 8 * 2);
    float* bias = (float*)alloc(JTOT * 4);
    int* locOff = (int*)alloc((size_t)N_ * 4);
    int* rowStart = (int*)alloc((size_t)(N_ + 1) * 4);
    int* csr_src = (int*)alloc((size_t)E_ * 4);
    int* csr_dst = (int*)alloc((size_t)E_ * 4);
    int* bucketTotal = (int*)alloc(NBKT * 4);
    int* bucketBase = (int*)alloc(NBKT * 4);
    int* bktFill = (int*)alloc(NBKT * 4);
    int2* ebkt = (int2*)alloc((size_t)NBKT * BCAP * 8);
    float* partH = (float*)alloc((size_t)B_ * HCHUNK * 1024 * 4);
    float* partAdj = (float*)alloc((size_t)B_ * ACHUNK * 2048 * 4);

    k_convx<<<NCVX + 384, 256, 0, stream>>>(x, xhi, xq, bktFill, We, be, Wp, bp, WThi, bias);
    k_binA<<<NBLK_A, 256, 0, stream>>>(ei, bktFill, ebkt);
    k_binB0<<<NBKT, 256, 0, stream>>>(bktFill, ebkt, locOff, bucketTotal);
    k_scanS<<<1, 128, 0, stream>>>(bucketTotal, bucketBase, rowStart);
    k_binB1<<<NBKT, 256, 0, stream>>>(bktFill, ebkt, locOff, bucketBase, rowStart, csr_src, csr_dst);
    k_agg<<<NAGG, 256, 0, stream>>>(xq, rowStart, csr_src, nhi);
    k_gemm<<<NGB, 256, 0, stream>>>(xhi, nhi, WThi, bias, embed, plog);
    k_r<<<(N_ + 3) / 4, 256, 0, stream>>>(plog, batch, r8, r8b);
    k_h_part<<<dim3(B_, HCHUNK), 256, 0, stream>>>(embed, r8, partH);
    k_adjm<<<dim3(B_, ACHUNK), 256, 0, stream>>>(rowStart, csr_src, csr_dst, r8b, partAdj);
    k_red<<<(256 * 256 + 256 * 128 + 255) / 256, 256, 0, stream>>>(partAdj, partH, out);
}

// Round 4
// 228.484 us; speedup vs baseline: 1.1206x; 1.1206x over previous
//
#include <hip/hip_runtime.h>
#include <hip/hip_bf16.h>

#define N_ 50000
#define E_ 800000
#define IN_ 128
#define OUT_ 128
#define ASSIGN_ 256
#define B_ 32
#define KTOT 256     // 2*IN
#define JTOT 384     // OUT + ASSIGN
#define HCHUNK 32
#define ACHUNK 32
#define AST 72       // k_adjm LDS row stride in u16
#define NXP ((N_ + 127) / 128)       // 391 row panels
#define NGB (NXP * 3)                // 1173 gemm blocks
#define NCVX 6250                    // (N*128/4)/256 exact

// edge bucket sort
#define NBKT 128
#define NPB 391
#define BCAP 7000
#define EPB 4096
#define NBLK_A ((E_ + EPB - 1) / EPB)  // 196
#define NPRE (NBLK_A + NCVX + 384)     // fused pre kernel grid

typedef __attribute__((ext_vector_type(8))) short short8;
typedef __attribute__((ext_vector_type(4))) float f32x4;
typedef __attribute__((ext_vector_type(2))) float f32x2;
typedef __attribute__((ext_vector_type(4))) unsigned short ushort4v;
typedef __attribute__((ext_vector_type(2))) unsigned short ushort2v;
typedef unsigned short u16;

__device__ inline unsigned short f2bf(float v) {
    union { float f; unsigned u; } a;
    a.f = v;
    unsigned r = a.u + 0x7fff + ((a.u >> 16) & 1);  // RNE
    return (unsigned short)(r >> 16);
}
__device__ inline float bf2f(unsigned short b) {
    union { unsigned u; float f; } a;
    a.u = ((unsigned)b) << 16;
    return a.f;
}

// ---- fp8 e4m3 encode (RNE via f32 bit trick; |v| < 448 assumed) ----
__device__ inline unsigned enc8(float v) {
    union { float f; unsigned u; } a;
    a.f = v * 0x1p-120f;
    unsigned b = a.u;
    unsigned r = b + 0x7FFFF + ((b >> 20) & 1);
    return ((r >> 20) & 0x7F) | ((b >> 24) & 0x80);
}
// ---- fp8 e4m3 pair decode ----
__device__ inline float2 dec8x2(unsigned short p) {
#if defined(__has_builtin) && __has_builtin(__builtin_amdgcn_cvt_pk_f32_fp8)
    f32x2 r = __builtin_amdgcn_cvt_pk_f32_fp8((int)(unsigned)p, false);
    return make_float2(r.x, r.y);
#else
    unsigned u0 = p & 0xffu, u1 = (p >> 8) & 0xffu;
    union { unsigned u; float f; } a, b;
    a.u = ((u0 & 0x80u) << 24) | ((u0 & 0x7fu) << 20);
    b.u = ((u1 & 0x80u) << 24) | ((u1 & 0x7fu) << 20);
    return make_float2(a.f * 0x1p+120f, b.f * 0x1p+120f);
#endif
}

// ---------------- fused pre: binA | x-convert | W prep ----------------
// binA blocks [0, NBLK_A): bin edges by dst-range. bktFill zero-init'd by memset;
// bucket base is implicit (t*BCAP + running count).
// convx blocks: x -> bf16 xhi + fp8 xq (flat [node][128]).
// prep blocks: W transposed bf16 + bias.
__global__ __launch_bounds__(256) void k_pre(const int* __restrict__ ei,
                                             int* __restrict__ bktFill,
                                             int2* __restrict__ ebkt,
                                             const float* __restrict__ x,
                                             unsigned short* __restrict__ xhi,
                                             unsigned char* __restrict__ xq,
                                             const float* __restrict__ We,
                                             const float* __restrict__ be,
                                             const float* __restrict__ Wp,
                                             const float* __restrict__ bp,
                                             unsigned short* __restrict__ WThi,
                                             float* __restrict__ bias) {
    __shared__ int lh[NBKT], lbase[NBKT], lofs[NBKT];
    int bid = blockIdx.x;
    int t = threadIdx.x;
    if (bid < NBLK_A) {
        int e0 = bid * EPB;
        if (t < NBKT) { lh[t] = 0; lofs[t] = 0; }
        __syncthreads();
        int ss[16], dd[16];
#pragma unroll
        for (int i = 0; i < 16; i++) {
            int e = e0 + i * 256 + t;
            ss[i] = 0; dd[i] = -1;
            if (e < E_) {
                ss[i] = ei[e];
                dd[i] = ei[E_ + e];
                atomicAdd(&lh[dd[i] / NPB], 1);
            }
        }
        __syncthreads();
        if (t < NBKT) lbase[t] = t * BCAP + atomicAdd(&bktFill[t], lh[t]);
        __syncthreads();
#pragma unroll
        for (int i = 0; i < 16; i++) {
            if (dd[i] >= 0) {
                int b = dd[i] / NPB;
                int o = atomicAdd(&lofs[b], 1);
                ebkt[lbase[b] + o] = make_int2(ss[i], dd[i]);
            }
        }
        return;
    }
    if (bid >= NBLK_A + NCVX) {  // prep tail
        int idx = (bid - NBLK_A - NCVX) * 256 + t;
        if (idx < JTOT * KTOT) {
            int j = idx / KTOT, k = idx - j * KTOT;
            float v = (j < 128) ? We[k * 128 + j] : Wp[k * 256 + (j - 128)];
            WThi[idx] = f2bf(v);
        }
        if (idx < JTOT) bias[idx] = (idx < 128) ? be[idx] : bp[idx - 128];
        return;
    }
    int i4 = ((bid - NBLK_A) * 256 + t) * 4;
    if (i4 >= N_ * 128) return;
    float4 v = *(const float4*)(x + i4);
    ushort4v h;
    h.x = f2bf(v.x); h.y = f2bf(v.y); h.z = f2bf(v.z); h.w = f2bf(v.w);
    *(ushort4v*)(xhi + i4) = h;
    unsigned q = enc8(v.x) | (enc8(v.y) << 8) | (enc8(v.z) << 16) | (enc8(v.w) << 24);
    *(unsigned*)(xq + i4) = q;
}

// ---------------- phase B0: per-bucket deg histogram + local exclusive scan ----------------
__global__ __launch_bounds__(256) void k_binB0(const int* __restrict__ bktFill,
                                               const int2* __restrict__ ebkt,
                                               int* __restrict__ locOff,
                                               int* __restrict__ bucketTotal) {
    __shared__ int ldeg[NPB];
    __shared__ int lscan[512];
    int b = blockIdx.x, t = threadIdx.x;
    for (int i = t; i < NPB; i += 256) ldeg[i] = 0;
    __syncthreads();
    int base = b * BCAP;
    int cnt = bktFill[b];
    int n0 = b * NPB;
    for (int j = t; j < cnt; j += 256)
        atomicAdd(&ldeg[ebkt[base + j].y - n0], 1);
    __syncthreads();
    lscan[t] = (t < NPB) ? ldeg[t] : 0;
    lscan[t + 256] = (t + 256 < NPB) ? ldeg[t + 256] : 0;
    __syncthreads();
    for (int off = 1; off < 512; off <<= 1) {
        int x0 = lscan[t];
        int x1 = lscan[t + 256];
        int a0 = (t >= off) ? lscan[t - off] : 0;
        int a1 = (t + 256 >= off) ? lscan[t + 256 - off] : 0;
        __syncthreads();
        lscan[t] = x0 + a0;
        lscan[t + 256] = x1 + a1;
        __syncthreads();
    }
    for (int i = t; i < NPB; i += 256) {
        int n = n0 + i;
        if (n < N_) locOff[n] = (i == 0) ? 0 : lscan[i - 1];
    }
    if (t == 0) bucketTotal[b] = lscan[NPB - 1];
}

// ---------------- phase B1 (+ inlined bucket scan): rowStart + CSR scatter ----------------
__global__ __launch_bounds__(256) void k_binB1(const int* __restrict__ bktFill,
                                               const int2* __restrict__ ebkt,
                                               const int* __restrict__ locOff,
                                               const int* __restrict__ bucketTotal,
                                               int* __restrict__ rowStart,
                                               int* __restrict__ csr_src,
                                               int* __restrict__ csr_dst) {
    __shared__ int lfill[NPB];
    __shared__ int bsc[NBKT];
    int b = blockIdx.x, t = threadIdx.x;
    if (t < NBKT) bsc[t] = bucketTotal[t];
    __syncthreads();
    for (int off = 1; off < NBKT; off <<= 1) {
        int x = (t < NBKT) ? bsc[t] : 0;
        int add = (t < NBKT && t >= off) ? bsc[t - off] : 0;
        __syncthreads();
        if (t < NBKT) bsc[t] = x + add;
        __syncthreads();
    }
    int base0 = (b == 0) ? 0 : bsc[b - 1];
    int n0 = b * NPB;
    for (int i = t; i < NPB; i += 256) {
        int n = n0 + i;
        if (n < N_) {
            int lo = locOff[n];
            lfill[i] = lo;
            rowStart[n] = base0 + lo;
        }
    }
    __syncthreads();
    int base = b * BCAP;
    int cnt = bktFill[b];
    for (int j = t; j < cnt; j += 256) {
        int2 sd = ebkt[base + j];
        int p = base0 + atomicAdd(&lfill[sd.y - n0], 1);
        csr_src[p] = sd.x;
        csr_dst[p] = sd.y;
    }
    if (b == 0 && t == 0) rowStart[N_] = E_;
}

// ---------------- neigh mean: dword gather, 1 node/wave, 2 edges/instr, 8 in flight ------
__global__ __launch_bounds__(256) void k_agg(const unsigned char* __restrict__ xq,
                                             const int* __restrict__ rowStart,
                                             const int* __restrict__ csr_src,
                                             unsigned short* __restrict__ nhi) {
    int node = blockIdx.x * 4 + (threadIdx.x >> 6);
    if (node >= N_) return;
    int lane = threadIdx.x & 63;
    int l5 = lane & 31;       // feature quad: f = 4*l5 .. 4*l5+3
    int eh = lane >> 5;       // edge slot 0/1
    int a = rowStart[node], bnd = rowStart[node + 1];
    float a0 = 0.f, a1 = 0.f, a2 = 0.f, a3 = 0.f;
    int j = a;
    for (; j + 7 < bnd; j += 8) {
        unsigned q[4];
#pragma unroll
        for (int ii = 0; ii < 4; ii++) {
            int s = csr_src[j + 2 * ii + eh];
            q[ii] = *(const unsigned*)(xq + (size_t)s * 128 + l5 * 4);
        }
#pragma unroll
        for (int ii = 0; ii < 4; ii++) {
            float2 f01 = dec8x2((unsigned short)(q[ii] & 0xffffu));
            float2 f23 = dec8x2((unsigned short)(q[ii] >> 16));
            a0 += f01.x; a1 += f01.y; a2 += f23.x; a3 += f23.y;
        }
    }
    for (; j < bnd; j += 2) {
        unsigned qq = 0;
        int e = j + eh;
        if (e < bnd) {
            int s = csr_src[e];
            qq = *(const unsigned*)(xq + (size_t)s * 128 + l5 * 4);
        }
        float2 f01 = dec8x2((unsigned short)(qq & 0xffffu));
        float2 f23 = dec8x2((unsigned short)(qq >> 16));
        a0 += f01.x; a1 += f01.y; a2 += f23.x; a3 += f23.y;
    }
    // combine the two edge slots
    a0 += __shfl_xor(a0, 32, 64);
    a1 += __shfl_xor(a1, 32, 64);
    a2 += __shfl_xor(a2, 32, 64);
    a3 += __shfl_xor(a3, 32, 64);
    float inv = 1.0f / (float)max(bnd - a, 1);
    if (lane < 32) {
        ushort4v h;
        h.x = f2bf(a0 * inv);
        h.y = f2bf(a1 * inv);
        h.z = f2bf(a2 * inv);
        h.w = f2bf(a3 * inv);
        *(ushort4v*)(nhi + (size_t)node * 128 + l5 * 4) = h;
    }
}

// ---------------- uniform 1-pass bf16 MFMA GEMM, XCD-swizzled, LDS epilogue ------
#define LDA 40  // 80 B rows
__global__ __launch_bounds__(256) void k_gemm(const unsigned short* __restrict__ xhi,
                                              const unsigned short* __restrict__ nhi,
                                              const unsigned short* __restrict__ WThi,
                                              const float* __restrict__ bias,
                                              unsigned short* __restrict__ embed,
                                              unsigned short* __restrict__ plog) {
    __shared__ __align__(16) union {
        struct { u16 Ah[128][LDA]; u16 Bh[128][LDA]; } s;
        u16 ep[64 * 128];  // 16 KB epilogue tile (64 rows x 128 cols)
    } sm;
    int t = threadIdx.x;
    int wave = t >> 6, lane = t & 63;
    int wm = wave >> 1, wn = wave & 1;
    int q = lane >> 4, lr = lane & 15;

    int id = blockIdx.x;
    int xi, cc;
    if (id < (NXP / 8) * 24) {           // 1152
        xi = (id / 24) * 8 + (id & 7);
        cc = (id % 24) >> 3;
    } else {
        int r2 = id - (NXP / 8) * 24;    // 0..20 over 7 tail panels
        xi = (NXP / 8) * 8 + r2 % (NXP % 8);
        cc = r2 / (NXP % 8);
    }
    int row0 = xi * 128;
    int col0 = cc * 128;

    f32x4 acc[4][4] = {};
    int smr = t >> 1;
    int kc = (t & 1) * 16;

    for (int kt = 0; kt < KTOT; kt += 32) {
        const u16* Ah_src = (kt < 128) ? xhi : nhi;
        int kb = (kt & 127) + kc;
        int node = row0 + smr;
        short8 vh0 = {}, vh1 = {};
        if (node < N_) {
            const short8* ph = (const short8*)(Ah_src + (size_t)node * 128 + kb);
            vh0 = ph[0]; vh1 = ph[1];
        }
        *(short8*)&sm.s.Ah[smr][kc] = vh0;
        *(short8*)&sm.s.Ah[smr][kc + 8] = vh1;
        {
            const short8* ph = (const short8*)(WThi + (size_t)(col0 + smr) * 256 + kt + kc);
            short8 wh0 = ph[0], wh1 = ph[1];
            *(short8*)&sm.s.Bh[smr][kc] = wh0;
            *(short8*)&sm.s.Bh[smr][kc + 8] = wh1;
        }
        __syncthreads();

        short8 afh[4];
#pragma unroll
        for (int mi = 0; mi < 4; mi++) {
            int r = wm * 64 + mi * 16 + lr;
            afh[mi] = *(const short8*)&sm.s.Ah[r][q * 8];
        }
#pragma unroll
        for (int ni = 0; ni < 4; ni++) {
            int r = wn * 64 + ni * 16 + lr;
            short8 bfh = *(const short8*)&sm.s.Bh[r][q * 8];
#pragma unroll
            for (int mi = 0; mi < 4; mi++)
                acc[mi][ni] = __builtin_amdgcn_mfma_f32_16x16x32_bf16(afh[mi], bfh, acc[mi][ni], 0, 0, 0);
        }
        __syncthreads();
    }

    // epilogue: two 64-row halves through LDS, full-line coalesced stores
    for (int half = 0; half < 2; half++) {
        __syncthreads();
        if (wm == half) {
#pragma unroll
            for (int mi = 0; mi < 4; mi++)
#pragma unroll
                for (int ni = 0; ni < 4; ni++) {
                    int lcol = wn * 64 + ni * 16 + lr;
                    float bj = bias[col0 + lcol];
#pragma unroll
                    for (int r = 0; r < 4; r++) {
                        int lrow = mi * 16 + q * 4 + r;
                        sm.ep[lrow * 128 + lcol] = f2bf(acc[mi][ni][r] + bj);
                    }
                }
        }
        __syncthreads();
#pragma unroll
        for (int i = 0; i < 4; i++) {
            int chunk = i * 256 + t;          // 0..1023
            int lrow = chunk >> 4;            // 64 rows x 16 chunks
            int lco = (chunk & 15) * 8;       // u16 offset
            int grow = row0 + half * 64 + lrow;
            if (grow < N_) {
                short8 v = *(const short8*)&sm.ep[lrow * 128 + lco];
                if (col0 < 128)
                    *(short8*)(embed + (size_t)grow * 128 + lco) = v;
                else
                    *(short8*)(plog + (size_t)grow * 256 + (col0 - 128) + lco) = v;
            }
        }
    }
}

// ---------------- double softmax -> compact r8[N][8] (fp32 + bf16 copy) ----------------
__global__ __launch_bounds__(256) void k_r(const unsigned short* __restrict__ plog,
                                           const int* __restrict__ batch,
                                           float* __restrict__ r8,
                                           unsigned short* __restrict__ r8b) {
    int node = blockIdx.x * 4 + (threadIdx.x >> 6);
    int lane = threadIdx.x & 63;
    if (node >= N_) return;
    ushort4v p4 = *(const ushort4v*)(plog + (size_t)node * 256 + lane * 4);
    float px = bf2f(p4.x), py = bf2f(p4.y), pz = bf2f(p4.z), pw = bf2f(p4.w);
    float m = fmaxf(fmaxf(px, py), fmaxf(pz, pw));
    for (int off = 32; off; off >>= 1) m = fmaxf(m, __shfl_xor(m, off, 64));
    float s = expf(px - m) + expf(py - m) + expf(pz - m) + expf(pw - m);
    for (int off = 32; off; off >>= 1) s += __shfl_xor(s, off, 64);
    int g = batch[node];
    float v = 0.f;
    if (lane < 8) v = expf(bf2f(plog[(size_t)node * 256 + g * 8 + lane]) - m) / s;
    float M2 = v;
    for (int off = 4; off; off >>= 1) M2 = fmaxf(M2, __shfl_xor(M2, off, 64));
    float e = expf(v - M2);
    float Sg = e;
    for (int off = 4; off; off >>= 1) Sg += __shfl_xor(Sg, off, 64);
    float D2 = Sg + 248.0f * expf(-M2);
    float r = e / (Sg + 1e-13f * D2);
    if (lane < 8) {
        r8[node * 8 + lane] = r;
        r8b[node * 8 + lane] = f2bf(r);
    }
}

// ---------------- fused tail: adjm (ids < 1024) | h_part (ids >= 1024) ----------------
__global__ __launch_bounds__(256) void k_tail(const int* __restrict__ rowStart,
                                              const int* __restrict__ csr_src,
                                              const int* __restrict__ csr_dst,
                                              const unsigned short* __restrict__ r8b,
                                              float* __restrict__ partAdj,
                                              const unsigned short* __restrict__ embed,
                                              const float* __restrict__ r8,
                                              float* __restrict__ partH) {
    __shared__ __align__(16) unsigned short Ab[256 * AST];  // [col=gs*8+a][e]
    __shared__ __align__(16) unsigned short Bb[16 * AST];   // [n=b][e]
    int id = blockIdx.x;
    int t = threadIdx.x;
    if (id >= B_ * ACHUNK) {
        // ---- h_part ----
        int idh = id - B_ * ACHUNK;
        int g = idh & 31;
        int c = idh >> 5;
        int o = t & 127, half = t >> 7;
        int n0g = (g * N_ + 31) >> 5;
        int n1g = ((g + 1) * N_ + 31) >> 5;
        int len = n1g - n0g;
        int a = n0g + (len * c) / HCHUNK;
        int b = n0g + (len * (c + 1)) / HCHUNK;
        float a0 = 0.f, a1 = 0.f, a2 = 0.f, a3 = 0.f;
#pragma unroll 4
        for (int n = a; n < b; n++) {
            float e = bf2f(embed[(size_t)n * 128 + o]);
            const float* rr = r8 + n * 8 + half;
            a0 += rr[0] * e;
            a1 += rr[2] * e;
            a2 += rr[4] * e;
            a3 += rr[6] * e;
        }
        float* pb = partH + (g * HCHUNK + c) * 1024;
        pb[(half + 0) * 128 + o] = a0;
        pb[(half + 2) * 128 + o] = a1;
        pb[(half + 4) * 128 + o] = a2;
        pb[(half + 6) * 128 + o] = a3;
        return;
    }
    // ---- adjm ----
    int gd = id & 31;
    int c = id >> 5;
    int wave = t >> 6, lane = t & 63;
    int q = lane >> 4, lr = lane & 15;
    int n0g = (gd * N_ + 31) >> 5;
    int n1g = ((gd + 1) * N_ + 31) >> 5;
    int len = n1g - n0g;
    int na = n0g + (len * c) / ACHUNK;
    int nb = n0g + (len * (c + 1)) / ACHUNK;
    int j0 = rowStart[na], j1 = rowStart[nb];

    // zero LDS ONCE; per-tile invariants maintained by zero-on-exit below
    uint4 z = {0, 0, 0, 0};
#pragma unroll
    for (int i = 0; i < 9; i++) *(uint4*)&Ab[(i * 256 + t) * 8] = z;
    if (t < 144) *(uint4*)&Bb[t * 8] = z;
    __syncthreads();

    f32x4 acc[4] = {};
    int el = t >> 2;
    int ap = t & 3;

    for (int jt = j0; jt < j1; jt += 64) {
        int j = jt + el;
        int ca = -1;
        if (j < j1) {
            int s = csr_src[j];
            int d = csr_dst[j];
            int gs = (s * B_) / N_;
            unsigned sv = *(const unsigned*)(r8b + (size_t)s * 8 + ap * 2);
            unsigned dv = *(const unsigned*)(r8b + (size_t)d * 8 + ap * 2);
            ca = gs * 8 + ap * 2;
            Ab[ca * AST + el] = (unsigned short)sv;
            Ab[(ca + 1) * AST + el] = (unsigned short)(sv >> 16);
            Bb[(ap * 2) * AST + el] = (unsigned short)dv;
            Bb[(ap * 2 + 1) * AST + el] = (unsigned short)(dv >> 16);
        }
        __syncthreads();
        short8 bf0 = *(const short8*)&Bb[lr * AST + q * 8];
        short8 bf1 = *(const short8*)&Bb[lr * AST + 32 + q * 8];
#pragma unroll
        for (int mi = 0; mi < 4; mi++) {
            int col = (wave * 4 + mi) * 16 + lr;
            short8 a0 = *(const short8*)&Ab[col * AST + q * 8];
            short8 a1 = *(const short8*)&Ab[col * AST + 32 + q * 8];
            acc[mi] = __builtin_amdgcn_mfma_f32_16x16x32_bf16(a0, bf0, acc[mi], 0, 0, 0);
            acc[mi] = __builtin_amdgcn_mfma_f32_16x16x32_bf16(a1, bf1, acc[mi], 0, 0, 0);
        }
        __syncthreads();
        if (ca >= 0) {  // zero-on-exit: clear exactly the slots this thread wrote
            Ab[ca * AST + el] = 0;
            Ab[(ca + 1) * AST + el] = 0;
            Bb[(ap * 2) * AST + el] = 0;
            Bb[(ap * 2 + 1) * AST + el] = 0;
        }
        __syncthreads();
    }

    float* pb = partAdj + (gd * ACHUNK + c) * 2048;
    if (lr < 8) {
#pragma unroll
        for (int mi = 0; mi < 4; mi++) {
            int mbase = (wave * 4 + mi) * 16 + q * 4;
#pragma unroll
            for (int r = 0; r < 4; r++)
                pb[(mbase + r) * 8 + lr] = acc[mi][r];
        }
    }
}

// ---------------- fused adj + h reduce ----------------
__global__ __launch_bounds__(256) void k_red(const float* __restrict__ partAdj,
                                             const float* __restrict__ partH,
                                             float* __restrict__ out) {
    int o = blockIdx.x * 256 + threadIdx.x;
    if (o < 256 * 256) {
        int row = o >> 8, col = o & 255;
        int gd = col >> 3, b = col & 7;
        int li = row * 8 + b;
        float s = 0.f;
#pragma unroll
        for (int c = 0; c < ACHUNK; c++) s += partAdj[(gd * ACHUNK + c) * 2048 + li];
        out[o] = s;
    } else {
        int idx = o - 256 * 256;            // < 32768 by grid sizing
        int g = idx >> 10;
        int local = idx & 1023;
        float s = 0.f;
#pragma unroll
        for (int c = 0; c < HCHUNK; c++) s += partH[(g * HCHUNK + c) * 1024 + local];
        out[256 * 256 + idx] = s;
    }
}

extern "C" void kernel_launch(void* const* d_in, const int* in_sizes, int n_in,
                              void* d_out, int out_size, void* d_ws, size_t ws_size,
                              hipStream_t stream) {
    const float* x = (const float*)d_in[0];
    const int* ei = (const int*)d_in[1];
    const int* batch = (const int*)d_in[2];
    const float* We = (const float*)d_in[3];
    const float* be = (const float*)d_in[4];
    const float* Wp = (const float*)d_in[5];
    const float* bp = (const float*)d_in[6];
    float* out = (float*)d_out;  // [adj 256*256 | h 256*128]

    char* w = (char*)d_ws;
    auto alloc = [&](size_t bytes) -> char* {
        char* p = w;
        w += (bytes + 255) & ~(size_t)255;
        return p;
    };
    unsigned short* xhi = (unsigned short*)alloc((size_t)N_ * 128 * 2);
    unsigned char* xq = (unsigned char*)alloc((size_t)N_ * 128);
    unsigned short* nhi = (unsigned short*)alloc((size_t)N_ * 128 * 2);
    unsigned short* WThi = (unsigned short*)alloc((size_t)JTOT * KTOT * 2);
    unsigned short* embed = (unsigned short*)alloc((size_t)N_ * 128 * 2);
    unsigned short* plog = (unsigned short*)alloc((size_t)N_ * 256 * 2);
    float* r8 = (float*)alloc((size_t)N_ * 8 * 4);
    unsigned short* r8b = (unsigned short*)alloc((size_t)N_ * 8 * 2);
    float* bias = (float*)alloc(JTOT * 4);
    int* locOff = (int*)alloc((size_t)N_ * 4);
    int* rowStart = (int*)alloc((size_t)(N_ + 1) * 4);
    int* csr_src = (int*)alloc((size_t)E_ * 4);
    int* csr_dst = (int*)alloc((size_t)E_ * 4);
    int* bucketTotal = (int*)alloc(NBKT * 4);
    int* bktFill = (int*)alloc(NBKT * 4);
    int2* ebkt = (int2*)alloc((size_t)NBKT * BCAP * 8);
    float* partH = (float*)alloc((size_t)B_ * HCHUNK * 1024 * 4);
    float* partAdj = (float*)alloc((size_t)B_ * ACHUNK * 2048 * 4);

    hipMemsetAsync(bktFill, 0, NBKT * 4, stream);
    k_pre<<<NPRE, 256, 0, stream>>>(ei, bktFill, ebkt, x, xhi, xq, We, be, Wp, bp, WThi, bias);
    k_binB0<<<NBKT, 256, 0, stream>>>(bktFill, ebkt, locOff, bucketTotal);
    k_binB1<<<NBKT, 256, 0, stream>>>(bktFill, ebkt, locOff, bucketTotal, rowStart, csr_src, csr_dst);
    k_agg<<<(N_ + 3) / 4, 256, 0, stream>>>(xq, rowStart, csr_src, nhi);
    k_gemm<<<NGB, 256, 0, stream>>>(xhi, nhi, WThi, bias, embed, plog);
    k_r<<<(N_ + 3) / 4, 256, 0, stream>>>(plog, batch, r8, r8b);
    k_tail<<<2 * B_ * ACHUNK, 256, 0, stream>>>(rowStart, csr_src, csr_dst, r8b, partAdj, embed, r8, partH);
    k_red<<<(256 * 256 + 256 * 128 + 255) / 256, 256, 0, stream>>>(partAdj, partH, out);
}

// Round 5
// 224.225 us; speedup vs baseline: 1.1419x; 1.0190x over previous
//
#include <hip/hip_runtime.h>
#include <hip/hip_bf16.h>

#define N_ 50000
#define E_ 800000
#define IN_ 128
#define OUT_ 128
#define ASSIGN_ 256
#define B_ 32
#define KTOT 256     // 2*IN
#define JTOT 384     // OUT + ASSIGN
#define HCHUNK 32
#define ACHUNK 32
#define AST 72       // k_adjm LDS row stride in u16
#define NXP ((N_ + 127) / 128)       // 391 row panels
#define NGB (NXP * 3)                // 1173 gemm blocks
#define NCVX 6250                    // (N*128/4)/256 exact

// edge bucket sort
#define NBKT 128
#define NPB 391
#define BCAP 7000
#define EPB 4096
#define NBLK_A ((E_ + EPB - 1) / EPB)  // 196
#define NPRE (NBLK_A + NCVX + 384)     // fused pre kernel grid

typedef __attribute__((ext_vector_type(8))) short short8;
typedef __attribute__((ext_vector_type(4))) float f32x4;
typedef __attribute__((ext_vector_type(2))) float f32x2;
typedef __attribute__((ext_vector_type(4))) unsigned short ushort4v;
typedef __attribute__((ext_vector_type(2))) unsigned short ushort2v;
typedef unsigned short u16;

__device__ inline unsigned short f2bf(float v) {
    union { float f; unsigned u; } a;
    a.f = v;
    unsigned r = a.u + 0x7fff + ((a.u >> 16) & 1);  // RNE
    return (unsigned short)(r >> 16);
}
__device__ inline float bf2f(unsigned short b) {
    union { unsigned u; float f; } a;
    a.u = ((unsigned)b) << 16;
    return a.f;
}

// ---- fp8 e4m3 encode (RNE via f32 bit trick; |v| < 448 assumed) ----
__device__ inline unsigned enc8(float v) {
    union { float f; unsigned u; } a;
    a.f = v * 0x1p-120f;
    unsigned b = a.u;
    unsigned r = b + 0x7FFFF + ((b >> 20) & 1);
    return ((r >> 20) & 0x7F) | ((b >> 24) & 0x80);
}
// ---- fp8 e4m3 pair decode ----
__device__ inline float2 dec8x2(unsigned short p) {
#if defined(__has_builtin) && __has_builtin(__builtin_amdgcn_cvt_pk_f32_fp8)
    f32x2 r = __builtin_amdgcn_cvt_pk_f32_fp8((int)(unsigned)p, false);
    return make_float2(r.x, r.y);
#else
    unsigned u0 = p & 0xffu, u1 = (p >> 8) & 0xffu;
    union { unsigned u; float f; } a, b;
    a.u = ((u0 & 0x80u) << 24) | ((u0 & 0x7fu) << 20);
    b.u = ((u1 & 0x80u) << 24) | ((u1 & 0x7fu) << 20);
    return make_float2(a.f * 0x1p+120f, b.f * 0x1p+120f);
#endif
}

// ---------------- fused pre: binA | x-convert | W prep ----------------
__global__ __launch_bounds__(256) void k_pre(const int* __restrict__ ei,
                                             int* __restrict__ bktFill,
                                             int2* __restrict__ ebkt,
                                             const float* __restrict__ x,
                                             unsigned short* __restrict__ xhi,
                                             unsigned char* __restrict__ xq,
                                             const float* __restrict__ We,
                                             const float* __restrict__ be,
                                             const float* __restrict__ Wp,
                                             const float* __restrict__ bp,
                                             unsigned short* __restrict__ WThi,
                                             float* __restrict__ bias) {
    __shared__ int lh[NBKT], lbase[NBKT], lofs[NBKT];
    int bid = blockIdx.x;
    int t = threadIdx.x;
    if (bid < NBLK_A) {
        int e0 = bid * EPB;
        if (t < NBKT) { lh[t] = 0; lofs[t] = 0; }
        __syncthreads();
        int ss[16], dd[16];
#pragma unroll
        for (int i = 0; i < 16; i++) {
            int e = e0 + i * 256 + t;
            ss[i] = 0; dd[i] = -1;
            if (e < E_) {
                ss[i] = ei[e];
                dd[i] = ei[E_ + e];
                atomicAdd(&lh[dd[i] / NPB], 1);
            }
        }
        __syncthreads();
        if (t < NBKT) lbase[t] = t * BCAP + atomicAdd(&bktFill[t], lh[t]);
        __syncthreads();
#pragma unroll
        for (int i = 0; i < 16; i++) {
            if (dd[i] >= 0) {
                int b = dd[i] / NPB;
                int o = atomicAdd(&lofs[b], 1);
                ebkt[lbase[b] + o] = make_int2(ss[i], dd[i]);
            }
        }
        return;
    }
    if (bid >= NBLK_A + NCVX) {  // prep tail
        int idx = (bid - NBLK_A - NCVX) * 256 + t;
        if (idx < JTOT * KTOT) {
            int j = idx / KTOT, k = idx - j * KTOT;
            float v = (j < 128) ? We[k * 128 + j] : Wp[k * 256 + (j - 128)];
            WThi[idx] = f2bf(v);
        }
        if (idx < JTOT) bias[idx] = (idx < 128) ? be[idx] : bp[idx - 128];
        return;
    }
    int i4 = ((bid - NBLK_A) * 256 + t) * 4;
    if (i4 >= N_ * 128) return;
    float4 v = *(const float4*)(x + i4);
    ushort4v h;
    h.x = f2bf(v.x); h.y = f2bf(v.y); h.z = f2bf(v.z); h.w = f2bf(v.w);
    *(ushort4v*)(xhi + i4) = h;
    unsigned q = enc8(v.x) | (enc8(v.y) << 8) | (enc8(v.z) << 16) | (enc8(v.w) << 24);
    *(unsigned*)(xq + i4) = q;
}

// ---------------- fused B: histogram + scan + publish/wait handshake + CSR scatter ----
// Each block publishes its bucket total (flag = total+1, device-scope atomicExch)
// BEFORE polling others' flags; grid (128) <= CU count so every block is resident
// and publish-before-wait guarantees progress. Polls use atomic RMW (coherent
// across XCDs); ready[] zeroed by the launch-head memset.
__global__ __launch_bounds__(256) void k_binB(const int* __restrict__ bktFill,
                                              const int2* __restrict__ ebkt,
                                              int* __restrict__ ready,
                                              int* __restrict__ rowStart,
                                              int* __restrict__ csr_src,
                                              int* __restrict__ csr_dst) {
    __shared__ int ldeg[NPB];
    __shared__ int lscan[512];
    __shared__ int bsc[NBKT];
    __shared__ int lfill[NPB];
    int b = blockIdx.x, t = threadIdx.x;
    for (int i = t; i < NPB; i += 256) ldeg[i] = 0;
    __syncthreads();
    int base = b * BCAP;
    int cnt = bktFill[b];
    int n0 = b * NPB;
    for (int j = t; j < cnt; j += 256)
        atomicAdd(&ldeg[ebkt[base + j].y - n0], 1);
    __syncthreads();
    lscan[t] = (t < NPB) ? ldeg[t] : 0;
    lscan[t + 256] = (t + 256 < NPB) ? ldeg[t + 256] : 0;
    __syncthreads();
    for (int off = 1; off < 512; off <<= 1) {
        int x0 = lscan[t];
        int x1 = lscan[t + 256];
        int a0 = (t >= off) ? lscan[t - off] : 0;
        int a1 = (t + 256 >= off) ? lscan[t + 256 - off] : 0;
        __syncthreads();
        lscan[t] = x0 + a0;
        lscan[t + 256] = x1 + a1;
        __syncthreads();
    }
    // publish own total, then wait for all
    if (t == 0) atomicExch(&ready[b], lscan[NPB - 1] + 1);
    if (t < NBKT) {
        int v;
        while ((v = atomicAdd(&ready[t], 0)) == 0) __builtin_amdgcn_s_sleep(8);
        bsc[t] = v - 1;
    }
    __syncthreads();
    for (int off = 1; off < NBKT; off <<= 1) {
        int x = (t < NBKT) ? bsc[t] : 0;
        int add = (t < NBKT && t >= off) ? bsc[t - off] : 0;
        __syncthreads();
        if (t < NBKT) bsc[t] = x + add;
        __syncthreads();
    }
    int base0 = (b == 0) ? 0 : bsc[b - 1];
    for (int i = t; i < NPB; i += 256) {
        int n = n0 + i;
        if (n < N_) {
            int excl = (i == 0) ? 0 : lscan[i - 1];
            lfill[i] = excl;
            rowStart[n] = base0 + excl;
        }
    }
    __syncthreads();
    for (int j = t; j < cnt; j += 256) {
        int2 sd = ebkt[base + j];
        int p = base0 + atomicAdd(&lfill[sd.y - n0], 1);
        csr_src[p] = sd.x;
        csr_dst[p] = sd.y;
    }
    if (b == 0 && t == 0) rowStart[N_] = E_;
}

// ---------------- neigh mean: dword gather, 1 node/wave, 2 edges/instr, 8 in flight ------
__global__ __launch_bounds__(256) void k_agg(const unsigned char* __restrict__ xq,
                                             const int* __restrict__ rowStart,
                                             const int* __restrict__ csr_src,
                                             unsigned short* __restrict__ nhi) {
    int node = blockIdx.x * 4 + (threadIdx.x >> 6);
    if (node >= N_) return;
    int lane = threadIdx.x & 63;
    int l5 = lane & 31;       // feature quad: f = 4*l5 .. 4*l5+3
    int eh = lane >> 5;       // edge slot 0/1
    int a = rowStart[node], bnd = rowStart[node + 1];
    float a0 = 0.f, a1 = 0.f, a2 = 0.f, a3 = 0.f;
    int j = a;
    for (; j + 7 < bnd; j += 8) {
        unsigned q[4];
#pragma unroll
        for (int ii = 0; ii < 4; ii++) {
            int s = csr_src[j + 2 * ii + eh];
            q[ii] = *(const unsigned*)(xq + (size_t)s * 128 + l5 * 4);
        }
#pragma unroll
        for (int ii = 0; ii < 4; ii++) {
            float2 f01 = dec8x2((unsigned short)(q[ii] & 0xffffu));
            float2 f23 = dec8x2((unsigned short)(q[ii] >> 16));
            a0 += f01.x; a1 += f01.y; a2 += f23.x; a3 += f23.y;
        }
    }
    for (; j < bnd; j += 2) {
        unsigned qq = 0;
        int e = j + eh;
        if (e < bnd) {
            int s = csr_src[e];
            qq = *(const unsigned*)(xq + (size_t)s * 128 + l5 * 4);
        }
        float2 f01 = dec8x2((unsigned short)(qq & 0xffffu));
        float2 f23 = dec8x2((unsigned short)(qq >> 16));
        a0 += f01.x; a1 += f01.y; a2 += f23.x; a3 += f23.y;
    }
    // combine the two edge slots
    a0 += __shfl_xor(a0, 32, 64);
    a1 += __shfl_xor(a1, 32, 64);
    a2 += __shfl_xor(a2, 32, 64);
    a3 += __shfl_xor(a3, 32, 64);
    float inv = 1.0f / (float)max(bnd - a, 1);
    if (lane < 32) {
        ushort4v h;
        h.x = f2bf(a0 * inv);
        h.y = f2bf(a1 * inv);
        h.z = f2bf(a2 * inv);
        h.w = f2bf(a3 * inv);
        *(ushort4v*)(nhi + (size_t)node * 128 + l5 * 4) = h;
    }
}

// ---------------- uniform 1-pass bf16 MFMA GEMM, XCD-swizzled, reg-dbuf staging ------
#define LDA 40  // 80 B rows
__global__ __launch_bounds__(256) void k_gemm(const unsigned short* __restrict__ xhi,
                                              const unsigned short* __restrict__ nhi,
                                              const unsigned short* __restrict__ WThi,
                                              const float* __restrict__ bias,
                                              unsigned short* __restrict__ embed,
                                              unsigned short* __restrict__ plog) {
    __shared__ __align__(16) union {
        struct { u16 Ah[128][LDA]; u16 Bh[128][LDA]; } s;
        u16 ep[64 * 128];  // 16 KB epilogue tile (64 rows x 128 cols)
    } sm;
    int t = threadIdx.x;
    int wave = t >> 6, lane = t & 63;
    int wm = wave >> 1, wn = wave & 1;
    int q = lane >> 4, lr = lane & 15;

    int id = blockIdx.x;
    int xi, cc;
    if (id < (NXP / 8) * 24) {           // 1152
        xi = (id / 24) * 8 + (id & 7);
        cc = (id % 24) >> 3;
    } else {
        int r2 = id - (NXP / 8) * 24;    // 0..20 over 7 tail panels
        xi = (NXP / 8) * 8 + r2 % (NXP % 8);
        cc = r2 / (NXP % 8);
    }
    int row0 = xi * 128;
    int col0 = cc * 128;

    f32x4 acc[4][4] = {};
    int smr = t >> 1;
    int kc = (t & 1) * 16;
    int node = row0 + smr;

    // reg-dbuf staging: loads for step kt+32 are issued right after the barrier
    // that opens step kt's compute, hiding flat-load latency under the MFMAs.
    short8 vh0, vh1, wh0, wh1;
#define LOADK(KT)                                                                    \
    {                                                                                \
        const u16* Ah_src = ((KT) < 128) ? xhi : nhi;                                \
        int kb = ((KT) & 127) + kc;                                                  \
        vh0 = {}; vh1 = {};                                                          \
        if (node < N_) {                                                             \
            const short8* ph = (const short8*)(Ah_src + (size_t)node * 128 + kb);    \
            vh0 = ph[0]; vh1 = ph[1];                                                \
        }                                                                            \
        const short8* pw = (const short8*)(WThi + (size_t)(col0 + smr) * 256 + (KT) + kc); \
        wh0 = pw[0]; wh1 = pw[1];                                                    \
    }
    LOADK(0);
    for (int kt = 0; kt < KTOT; kt += 32) {
        *(short8*)&sm.s.Ah[smr][kc] = vh0;
        *(short8*)&sm.s.Ah[smr][kc + 8] = vh1;
        *(short8*)&sm.s.Bh[smr][kc] = wh0;
        *(short8*)&sm.s.Bh[smr][kc + 8] = wh1;
        __syncthreads();
        if (kt + 32 < KTOT) LOADK(kt + 32);

        short8 afh[4];
#pragma unroll
        for (int mi = 0; mi < 4; mi++) {
            int r = wm * 64 + mi * 16 + lr;
            afh[mi] = *(const short8*)&sm.s.Ah[r][q * 8];
        }
#pragma unroll
        for (int ni = 0; ni < 4; ni++) {
            int r = wn * 64 + ni * 16 + lr;
            short8 bfh = *(const short8*)&sm.s.Bh[r][q * 8];
#pragma unroll
            for (int mi = 0; mi < 4; mi++)
                acc[mi][ni] = __builtin_amdgcn_mfma_f32_16x16x32_bf16(afh[mi], bfh, acc[mi][ni], 0, 0, 0);
        }
        __syncthreads();
    }
#undef LOADK

    // epilogue: two 64-row halves through LDS, full-line coalesced stores
    for (int half = 0; half < 2; half++) {
        __syncthreads();
        if (wm == half) {
#pragma unroll
            for (int mi = 0; mi < 4; mi++)
#pragma unroll
                for (int ni = 0; ni < 4; ni++) {
                    int lcol = wn * 64 + ni * 16 + lr;
                    float bj = bias[col0 + lcol];
#pragma unroll
                    for (int r = 0; r < 4; r++) {
                        int lrow = mi * 16 + q * 4 + r;
                        sm.ep[lrow * 128 + lcol] = f2bf(acc[mi][ni][r] + bj);
                    }
                }
        }
        __syncthreads();
#pragma unroll
        for (int i = 0; i < 4; i++) {
            int chunk = i * 256 + t;          // 0..1023
            int lrow = chunk >> 4;            // 64 rows x 16 chunks
            int lco = (chunk & 15) * 8;       // u16 offset
            int grow = row0 + half * 64 + lrow;
            if (grow < N_) {
                short8 v = *(const short8*)&sm.ep[lrow * 128 + lco];
                if (col0 < 128)
                    *(short8*)(embed + (size_t)grow * 128 + lco) = v;
                else
                    *(short8*)(plog + (size_t)grow * 256 + (col0 - 128) + lco) = v;
            }
        }
    }
}

// ---------------- double softmax -> compact r8[N][8] (fp32 + bf16 copy) ----------------
__global__ __launch_bounds__(256) void k_r(const unsigned short* __restrict__ plog,
                                           const int* __restrict__ batch,
                                           float* __restrict__ r8,
                                           unsigned short* __restrict__ r8b) {
    int node = blockIdx.x * 4 + (threadIdx.x >> 6);
    int lane = threadIdx.x & 63;
    if (node >= N_) return;
    ushort4v p4 = *(const ushort4v*)(plog + (size_t)node * 256 + lane * 4);
    float px = bf2f(p4.x), py = bf2f(p4.y), pz = bf2f(p4.z), pw = bf2f(p4.w);
    float m = fmaxf(fmaxf(px, py), fmaxf(pz, pw));
    for (int off = 32; off; off >>= 1) m = fmaxf(m, __shfl_xor(m, off, 64));
    float s = expf(px - m) + expf(py - m) + expf(pz - m) + expf(pw - m);
    for (int off = 32; off; off >>= 1) s += __shfl_xor(s, off, 64);
    int g = batch[node];
    float v = 0.f;
    if (lane < 8) v = expf(bf2f(plog[(size_t)node * 256 + g * 8 + lane]) - m) / s;
    float M2 = v;
    for (int off = 4; off; off >>= 1) M2 = fmaxf(M2, __shfl_xor(M2, off, 64));
    float e = expf(v - M2);
    float Sg = e;
    for (int off = 4; off; off >>= 1) Sg += __shfl_xor(Sg, off, 64);
    float D2 = Sg + 248.0f * expf(-M2);
    float r = e / (Sg + 1e-13f * D2);
    if (lane < 8) {
        r8[node * 8 + lane] = r;
        r8b[node * 8 + lane] = f2bf(r);
    }
}

// ---------------- fused tail: adjm (ids < 1024) | h_part (ids >= 1024) ----------------
__global__ __launch_bounds__(256) void k_tail(const int* __restrict__ rowStart,
                                              const int* __restrict__ csr_src,
                                              const int* __restrict__ csr_dst,
                                              const unsigned short* __restrict__ r8b,
                                              float* __restrict__ partAdj,
                                              const unsigned short* __restrict__ embed,
                                              const float* __restrict__ r8,
                                              float* __restrict__ partH) {
    __shared__ __align__(16) unsigned short Ab[256 * AST];  // [col=gs*8+a][e]
    __shared__ __align__(16) unsigned short Bb[16 * AST];   // [n=b][e]
    int id = blockIdx.x;
    int t = threadIdx.x;
    if (id >= B_ * ACHUNK) {
        // ---- h_part ----
        int idh = id - B_ * ACHUNK;
        int g = idh & 31;
        int c = idh >> 5;
        int o = t & 127, half = t >> 7;
        int n0g = (g * N_ + 31) >> 5;
        int n1g = ((g + 1) * N_ + 31) >> 5;
        int len = n1g - n0g;
        int a = n0g + (len * c) / HCHUNK;
        int b = n0g + (len * (c + 1)) / HCHUNK;
        float a0 = 0.f, a1 = 0.f, a2 = 0.f, a3 = 0.f;
#pragma unroll 4
        for (int n = a; n < b; n++) {
            float e = bf2f(embed[(size_t)n * 128 + o]);
            const float* rr = r8 + n * 8 + half;
            a0 += rr[0] * e;
            a1 += rr[2] * e;
            a2 += rr[4] * e;
            a3 += rr[6] * e;
        }
        float* pb = partH + (g * HCHUNK + c) * 1024;
        pb[(half + 0) * 128 + o] = a0;
        pb[(half + 2) * 128 + o] = a1;
        pb[(half + 4) * 128 + o] = a2;
        pb[(half + 6) * 128 + o] = a3;
        return;
    }
    // ---- adjm ----
    int gd = id & 31;
    int c = id >> 5;
    int wave = t >> 6, lane = t & 63;
    int q = lane >> 4, lr = lane & 15;
    int n0g = (gd * N_ + 31) >> 5;
    int n1g = ((gd + 1) * N_ + 31) >> 5;
    int len = n1g - n0g;
    int na = n0g + (len * c) / ACHUNK;
    int nb = n0g + (len * (c + 1)) / ACHUNK;
    int j0 = rowStart[na], j1 = rowStart[nb];

    // zero LDS ONCE; per-tile invariants maintained by zero-on-exit below
    uint4 z = {0, 0, 0, 0};
#pragma unroll
    for (int i = 0; i < 9; i++) *(uint4*)&Ab[(i * 256 + t) * 8] = z;
    if (t < 144) *(uint4*)&Bb[t * 8] = z;
    __syncthreads();

    f32x4 acc[4] = {};
    int el = t >> 2;
    int ap = t & 3;

    for (int jt = j0; jt < j1; jt += 64) {
        int j = jt + el;
        int ca = -1;
        if (j < j1) {
            int s = csr_src[j];
            int d = csr_dst[j];
            int gs = (s * B_) / N_;
            unsigned sv = *(const unsigned*)(r8b + (size_t)s * 8 + ap * 2);
            unsigned dv = *(const unsigned*)(r8b + (size_t)d * 8 + ap * 2);
            ca = gs * 8 + ap * 2;
            Ab[ca * AST + el] = (unsigned short)sv;
            Ab[(ca + 1) * AST + el] = (unsigned short)(sv >> 16);
            Bb[(ap * 2) * AST + el] = (unsigned short)dv;
            Bb[(ap * 2 + 1) * AST + el] = (unsigned short)(dv >> 16);
        }
        __syncthreads();
        short8 bf0 = *(const short8*)&Bb[lr * AST + q * 8];
        short8 bf1 = *(const short8*)&Bb[lr * AST + 32 + q * 8];
#pragma unroll
        for (int mi = 0; mi < 4; mi++) {
            int col = (wave * 4 + mi) * 16 + lr;
            short8 a0 = *(const short8*)&Ab[col * AST + q * 8];
            short8 a1 = *(const short8*)&Ab[col * AST + 32 + q * 8];
            acc[mi] = __builtin_amdgcn_mfma_f32_16x16x32_bf16(a0, bf0, acc[mi], 0, 0, 0);
            acc[mi] = __builtin_amdgcn_mfma_f32_16x16x32_bf16(a1, bf1, acc[mi], 0, 0, 0);
        }
        __syncthreads();
        if (ca >= 0) {  // zero-on-exit: clear exactly the slots this thread wrote
            Ab[ca * AST + el] = 0;
            Ab[(ca + 1) * AST + el] = 0;
            Bb[(ap * 2) * AST + el] = 0;
            Bb[(ap * 2 + 1) * AST + el] = 0;
        }
        __syncthreads();
    }

    float* pb = partAdj + (gd * ACHUNK + c) * 2048;
    if (lr < 8) {
#pragma unroll
        for (int mi = 0; mi < 4; mi++) {
            int mbase = (wave * 4 + mi) * 16 + q * 4;
#pragma unroll
            for (int r = 0; r < 4; r++)
                pb[(mbase + r) * 8 + lr] = acc[mi][r];
        }
    }
}

// ---------------- fused adj + h reduce ----------------
__global__ __launch_bounds__(256) void k_red(const float* __restrict__ partAdj,
                                             const float* __restrict__ partH,
                                             float* __restrict__ out) {
    int o = blockIdx.x * 256 + threadIdx.x;
    if (o < 256 * 256) {
        int row = o >> 8, col = o & 255;
        int gd = col >> 3, b = col & 7;
        int li = row * 8 + b;
        float s = 0.f;
#pragma unroll
        for (int c = 0; c < ACHUNK; c++) s += partAdj[(gd * ACHUNK + c) * 2048 + li];
        out[o] = s;
    } else {
        int idx = o - 256 * 256;            // < 32768 by grid sizing
        int g = idx >> 10;
        int local = idx & 1023;
        float s = 0.f;
#pragma unroll
        for (int c = 0; c < HCHUNK; c++) s += partH[(g * HCHUNK + c) * 1024 + local];
        out[256 * 256 + idx] = s;
    }
}

extern "C" void kernel_launch(void* const* d_in, const int* in_sizes, int n_in,
                              void* d_out, int out_size, void* d_ws, size_t ws_size,
                              hipStream_t stream) {
    const float* x = (const float*)d_in[0];
    const int* ei = (const int*)d_in[1];
    const int* batch = (const int*)d_in[2];
    const float* We = (const float*)d_in[3];
    const float* be = (const float*)d_in[4];
    const float* Wp = (const float*)d_in[5];
    const float* bp = (const float*)d_in[6];
    float* out = (float*)d_out;  // [adj 256*256 | h 256*128]

    char* w = (char*)d_ws;
    auto alloc = [&](size_t bytes) -> char* {
        char* p = w;
        w += (bytes + 255) & ~(size_t)255;
        return p;
    };
    unsigned short* xhi = (unsigned short*)alloc((size_t)N_ * 128 * 2);
    unsigned char* xq = (unsigned char*)alloc((size_t)N_ * 128);
    unsigned short* nhi = (unsigned short*)alloc((size_t)N_ * 128 * 2);
    unsigned short* WThi = (unsigned short*)alloc((size_t)JTOT * KTOT * 2);
    unsigned short* embed = (unsigned short*)alloc((size_t)N_ * 128 * 2);
    unsigned short* plog = (unsigned short*)alloc((size_t)N_ * 256 * 2);
    float* r8 = (float*)alloc((size_t)N_ * 8 * 4);
    unsigned short* r8b = (unsigned short*)alloc((size_t)N_ * 8 * 2);
    float* bias = (float*)alloc(JTOT * 4);
    int* rowStart = (int*)alloc((size_t)(N_ + 1) * 4);
    int* csr_src = (int*)alloc((size_t)E_ * 4);
    int* csr_dst = (int*)alloc((size_t)E_ * 4);
    int* bktFill = (int*)alloc(2 * NBKT * 4);   // [bktFill | ready] contiguous
    int* ready = bktFill + NBKT;
    int2* ebkt = (int2*)alloc((size_t)NBKT * BCAP * 8);
    float* partH = (float*)alloc((size_t)B_ * HCHUNK * 1024 * 4);
    float* partAdj = (float*)alloc((size_t)B_ * ACHUNK * 2048 * 4);

    hipMemsetAsync(bktFill, 0, 2 * NBKT * 4, stream);
    k_pre<<<NPRE, 256, 0, stream>>>(ei, bktFill, ebkt, x, xhi, xq, We, be, Wp, bp, WThi, bias);
    k_binB<<<NBKT, 256, 0, stream>>>(bktFill, ebkt, ready, rowStart, csr_src, csr_dst);
    k_agg<<<(N_ + 3) / 4, 256, 0, stream>>>(xq, rowStart, csr_src, nhi);
    k_gemm<<<NGB, 256, 0, stream>>>(xhi, nhi, WThi, bias, embed, plog);
    k_r<<<(N_ + 3) / 4, 256, 0, stream>>>(plog, batch, r8, r8b);
    k_tail<<<2 * B_ * ACHUNK, 256, 0, stream>>>(rowStart, csr_src, csr_dst, r8b, partAdj, embed, r8, partH);
    k_red<<<(256 * 256 + 256 * 128 + 255) / 256, 256, 0, stream>>>(partAdj, partH, out);
}